// Round 6
// baseline (270.394 us; speedup 1.0000x reference)
//
#include <hip/hip_runtime.h>
#include <stdint.h>

#define NB 4
#define NSEQ 2048
#define DIN 384
#define DV 384
#define NH 8
#define DH 48
#define DFF 1536
#define MTOT (NB*NSEQ)   // 8192
#define QBLK 128

typedef __attribute__((ext_vector_type(8))) short bf16x8;
typedef __attribute__((ext_vector_type(4))) float f32x4;
typedef unsigned short u16;

#define SCALE2 0.07362222f   // (1/sqrt(384)) * log2(e): softmax in exp2 domain

__device__ __forceinline__ u16 f2bf(float f) {
  unsigned u = __builtin_bit_cast(unsigned, f);
  u = (u + 0x7FFFu + ((u >> 16) & 1u)) >> 16;
  return (u16)u;
}
__device__ __forceinline__ float bf2f(u16 h) {
  unsigned u = ((unsigned)h) << 16;
  return __builtin_bit_cast(float, u);
}
__device__ __forceinline__ float ex2(float x) {   // 2^x, single v_exp_f32
  float r; asm("v_exp_f32 %0, %1" : "=v"(r) : "v"(x)); return r;
}
__device__ __forceinline__ float frcp(float x) {  // fast 1/x
  float r; asm("v_rcp_f32 %0, %1" : "=v"(r) : "v"(x)); return r;
}

// async global->LDS, 16B per lane; LDS dest must be lane-linear (base + lane*16)
__device__ __forceinline__ void gload16(const u16* g, u16* l) {
  __builtin_amdgcn_global_load_lds(
      (const __attribute__((address_space(1))) void*)g,
      (__attribute__((address_space(3))) void*)l, 16, 0, 0);
}

// ---------------- convert f32 -> bf16 (x, y, Wq, Wk, Wv, W1, W2) ----------------
__global__ __launch_bounds__(256) void convert_k(
    const float* __restrict__ xf, const float* __restrict__ yf,
    const float* __restrict__ wq, const float* __restrict__ wk,
    const float* __restrict__ wv, const float* __restrict__ w1,
    const float* __restrict__ w2,
    u16* __restrict__ xb, u16* __restrict__ yb,
    u16* __restrict__ wqb, u16* __restrict__ wkb, u16* __restrict__ wvb,
    u16* __restrict__ w1b, u16* __restrict__ w2b) {
  long i = (long)blockIdx.x * 256 + threadIdx.x;  // 4-elem unit
  const float* src; u16* dst; long u = i;
  if      (u < 786432)  { src = xf; dst = xb; }
  else if (u < 1572864) { u -= 786432;  src = yf; dst = yb; }
  else if (u < 1609728) { u -= 1572864; src = wq; dst = wqb; }
  else if (u < 1646592) { u -= 1609728; src = wk; dst = wkb; }
  else if (u < 1683456) { u -= 1646592; src = wv; dst = wvb; }
  else if (u < 1830912) { u -= 1683456; src = w1; dst = w1b; }
  else                  { u -= 1830912; src = w2; dst = w2b; }
  float4 v = ((const float4*)src)[u];
  ushort4 o;
  o.x = f2bf(v.x); o.y = f2bf(v.y); o.z = f2bf(v.z); o.w = f2bf(v.w);
  ((ushort4*)dst)[u] = o;
}

// ---------------- generic C = A(MxK) * B(NxK)^T tile (128x128, BK=64) ----------------
// A row stride = ldk (enables split-K).  EPI: 0 = store bf16; 1 = gelu(tanh) bf16;
// 2 = atomicAdd f32; 3 = V^T store (VT[b*384+gn][gm&2047])
template<int EPI>
__device__ __forceinline__ void gemm_tile(const u16* __restrict__ A,
                                          const u16* __restrict__ Bw,
                                          int K, int ldk,
                                          int m0, int n0, int ldc,
                                          u16* __restrict__ Cb,
                                          float* __restrict__ Cf) {
  __shared__ __align__(16) u16 Al[128 * 64];
  __shared__ __align__(16) u16 Bl[128 * 64];
  const int t = threadIdx.x;
  const int l = t & 63, w = t >> 6;
  const int g = l >> 4, nn = l & 15;
  const int wm = w >> 1, wn = w & 1;
  f32x4 acc[4][4] = {};
  const int KT = K >> 6;
  for (int kt = 0; kt < KT; ++kt) {
    const int k0 = kt * 64;
    __syncthreads();   // previous iteration's frag reads done
#pragma unroll
    for (int s = 0; s < 4; ++s) {
      int u = t + 256 * s; int r = u >> 3, ch = u & 7;
      int csw = (ch ^ (r & 7)) * 8;     // inverse-swizzled source column
      gload16(A  + (long)(m0 + r) * ldk + k0 + csw, Al + u * 8);
      gload16(Bw + (long)(n0 + r) * ldk + k0 + csw, Bl + u * 8);
    }
    __syncthreads();   // vmcnt drained, staged data visible
#pragma unroll
    for (int ks = 0; ks < 2; ++ks) {
      const int slot = ((ks * 4 + g) ^ (nn & 7)) * 8;
      bf16x8 af[4], bfr[4];
#pragma unroll
      for (int mt = 0; mt < 4; ++mt)
        af[mt] = *(const bf16x8*)(Al + (wm * 64 + mt * 16 + nn) * 64 + slot);
#pragma unroll
      for (int nt = 0; nt < 4; ++nt)
        bfr[nt] = *(const bf16x8*)(Bl + (wn * 64 + nt * 16 + nn) * 64 + slot);
#pragma unroll
      for (int mt = 0; mt < 4; ++mt)
#pragma unroll
        for (int nt = 0; nt < 4; ++nt)
          acc[mt][nt] = __builtin_amdgcn_mfma_f32_16x16x32_bf16(af[mt], bfr[nt], acc[mt][nt], 0, 0, 0);
    }
  }
  // epilogue
#pragma unroll
  for (int mt = 0; mt < 4; ++mt)
#pragma unroll
    for (int nt = 0; nt < 4; ++nt)
#pragma unroll
      for (int jr = 0; jr < 4; ++jr) {
        int gm = m0 + wm * 64 + mt * 16 + g * 4 + jr;
        int gn = n0 + wn * 64 + nt * 16 + nn;
        float v = acc[mt][nt][jr];
        if (EPI == 0) {
          Cb[(long)gm * ldc + gn] = f2bf(v);
        } else if (EPI == 1) {
          // gelu via tanh approx: 0.5v(1+tanh(0.79788456(v+0.044715 v^3)))
          float inner = 0.7978845608f * v * (1.0f + 0.044715f * v * v);
          float tl = ex2(-2.885390082f * fabsf(inner));   // e^{-2|inner|}
          float th = (1.0f - tl) * frcp(1.0f + tl);
          th = copysignf(th, inner);
          Cb[(long)gm * ldc + gn] = f2bf(0.5f * v * (1.0f + th));
        } else if (EPI == 2) {
          unsafeAtomicAdd(&Cf[(long)gm * ldc + gn], v);
        } else {
          // V^T: VT[(b*384 + gn)][n], b = gm>>11, n = gm&2047
          long vidx = ((long)(gm >> 11) * 384 + gn) * 2048 + (gm & 2047);
          Cb[vidx] = f2bf(v);
        }
      }
}

// Q,K projections: by in [0,6): mat = by/3 (0=Q from x, 1=K from y), ntile = by%3
__global__ __launch_bounds__(256) void qkv_k(const u16* __restrict__ xb,
                                             const u16* __restrict__ yb,
                                             const u16* __restrict__ Wb,
                                             u16* __restrict__ QKVb) {
  int bx = blockIdx.x;          // 0..63 (M tiles)
  int by = blockIdx.y;          // 0..5
  int mat = by / 3, ntile = by - mat * 3;
  const u16* A = (mat == 0) ? xb : yb;
  const u16* Bw = Wb + (long)mat * (DV * DIN);
  u16* C = QKVb + (long)mat * ((long)MTOT * DV);
  gemm_tile<0>(A, Bw, DIN, DIN, bx * 128, ntile * 128, DV, C, nullptr);
}

// V projection, written transposed per (b,h): VT[b][h][d][n]
__global__ __launch_bounds__(256) void vt_k(const u16* __restrict__ yb,
                                            const u16* __restrict__ Wvb,
                                            u16* __restrict__ VT) {
  gemm_tile<3>(yb, Wvb, DIN, DIN, blockIdx.x * 128, blockIdx.y * 128, 0, VT, nullptr);
}

__global__ __launch_bounds__(256) void ffn1_k(const u16* __restrict__ Ob,
                                              const u16* __restrict__ W1b,
                                              u16* __restrict__ hid) {
  gemm_tile<1>(Ob, W1b, DV, DV, blockIdx.x * 128, blockIdx.y * 128, DFF, hid, nullptr);
}

// split-K x2: z in {0,1}, K-half = 768, atomicAdd into Out
__global__ __launch_bounds__(256) void ffn2_k(const u16* __restrict__ hid,
                                              const u16* __restrict__ W2b,
                                              float* __restrict__ Out) {
  int z = blockIdx.z;
  gemm_tile<2>(hid + z * 768, W2b + z * 768, 768, DFF,
               blockIdx.x * 128, blockIdx.y * 128, DV, nullptr, Out);
}

// ---------------- single-pass flash attention v3 ----------------
// 512 blocks = (b,h,128-row q-tile); 8 waves x 16-row stripes.
// K: global_load_lds double-buffer, 1 barrier/chunk. V: read direct from VT (L2).
// Softmax in exp2 domain; P truncation-rounded to bf16 in LDS (wave-private).
__global__ __launch_bounds__(512) void attn_k(const u16* __restrict__ Qb,
                                              const u16* __restrict__ Kb,
                                              const u16* __restrict__ VT,
                                              u16* __restrict__ Ob,
                                              float* __restrict__ Out) {
  __shared__ __align__(16) u16 Kl[2][128 * 64];  // dbuf 32KB, swizzled slots
  __shared__ __align__(16) u16 Pl[128 * 128];    // 32KB; Q scratch first

  int bx0 = blockIdx.x;
  int lg = (bx0 & 7) * 64 + (bx0 >> 3);          // XCD swizzle (512 = 8*64, bijective)
  int qt = lg & 15, h = (lg >> 4) & 7, b = lg >> 7;
  const int t = threadIdx.x, l = t & 63, w = t >> 6;
  const int g = l >> 4, n = l & 15;
  const long rowbase = (long)b * NSEQ;
  const int q0 = qt * QBLK;
  const int hc = h * DH;
  const u16* vt = VT + (long)(b * NH + h) * (DH * NSEQ);   // [48][2048]

  // stage Q (pre-scaled into exp2 domain) into Pl scratch [128][64] + zero pad
  for (int i = t; i < 768; i += 512) {
    int r = i / 6, ch = i - r * 6;
    bf16x8 v = *(const bf16x8*)(Qb + (rowbase + q0 + r) * DV + hc + ch * 8);
    bf16x8 sv;
#pragma unroll
    for (int e = 0; e < 8; ++e) sv[e] = (short)f2bf(bf2f((u16)v[e]) * SCALE2);
    *(bf16x8*)(Pl + r * 64 + ch * 8) = sv;
  }
  if (t < 256) {                                  // zero cols 48..63
    int r = t >> 1;
    bf16x8 z = {};
    *(bf16x8*)(Pl + r * 64 + 48 + (t & 1) * 8) = z;
  }
  // issue chunk-0 K stage (async, all 8 slots; cols 48-63 garbage x Q-zeros = 0)
#pragma unroll
  for (int s = 0; s < 2; ++s) {
    int u = t + 512 * s; int r = u >> 3, ch = u & 7;
    gload16(Kb + (rowbase + r) * DV + hc + ((ch ^ (r & 7)) * 8), &Kl[0][u * 8]);
  }
  __syncthreads();   // Q visible (also drains stage(0) — prologue only)

  bf16x8 qa[2];
#pragma unroll
  for (int ks = 0; ks < 2; ++ks)
    qa[ks] = *(const bf16x8*)(Pl + (w * 16 + n) * 64 + ks * 32 + g * 8);

  float mL[4], sL[4];
#pragma unroll
  for (int jr = 0; jr < 4; ++jr) { mL[jr] = -1e30f; sL[jr] = 0.0f; }
  f32x4 oacc[3] = {};

  for (int c = 0; c < 16; ++c) {
    asm volatile("s_waitcnt vmcnt(0)" ::: "memory");  // own stage(c) landed
    __builtin_amdgcn_s_barrier();                     // everyone's stage(c) landed;
    __builtin_amdgcn_sched_barrier(0);                // buf[c^1] reads all done
    if (c + 1 < 16) {   // issue stage(c+1) into other buf; overlaps this chunk's compute
      u16* dst = Kl[(c + 1) & 1];
#pragma unroll
      for (int s = 0; s < 2; ++s) {
        int u = t + 512 * s; int r = u >> 3, ch = u & 7;
        gload16(Kb + (rowbase + (c + 1) * 128 + r) * DV + hc + ((ch ^ (r & 7)) * 8),
                dst + u * 8);
      }
    }
    const u16* kbuf = Kl[c & 1];

    // QK^T: 16 q-rows x 128 k-cols
    f32x4 sc[8];
#pragma unroll
    for (int jl = 0; jl < 8; ++jl) {
      f32x4 a = {};
#pragma unroll
      for (int ks = 0; ks < 2; ++ks) {
        bf16x8 kb2 = *(const bf16x8*)(kbuf + (jl * 16 + n) * 64 + (((ks * 4 + g) ^ (n & 7)) * 8));
        a = __builtin_amdgcn_mfma_f32_16x16x32_bf16(qa[ks], kb2, a, 0, 0, 0);
      }
      sc[jl] = a;
    }

    // online softmax (exp2 domain), P -> LDS (trunc bf16, swizzled), O rescale
#pragma unroll
    for (int jr = 0; jr < 4; ++jr) {
      float mx = fmaxf(fmaxf(fmaxf(sc[0][jr], sc[1][jr]), fmaxf(sc[2][jr], sc[3][jr])),
                       fmaxf(fmaxf(sc[4][jr], sc[5][jr]), fmaxf(sc[6][jr], sc[7][jr])));
      mx = fmaxf(mx, __shfl_xor(mx, 1, 64));
      mx = fmaxf(mx, __shfl_xor(mx, 2, 64));
      mx = fmaxf(mx, __shfl_xor(mx, 4, 64));
      mx = fmaxf(mx, __shfl_xor(mx, 8, 64));
      float mn = fmaxf(mL[jr], mx);
      float scl = ex2(mL[jr] - mn);
      mL[jr] = mn;
      float rs = 0.0f;
      u16* prl = Pl + (w * 16 + 4 * g + jr) * 128;
      const int pswz = ((4 * g + jr) & 7) << 3;
#pragma unroll
      for (int jl = 0; jl < 8; ++jl) {
        float p = ex2(sc[jl][jr] - mn);
        rs += p;
        prl[(jl * 16 + n) ^ pswz] = (u16)(__builtin_bit_cast(unsigned, p) >> 16);
      }
      rs += __shfl_xor(rs, 1, 64);
      rs += __shfl_xor(rs, 2, 64);
      rs += __shfl_xor(rs, 4, 64);
      rs += __shfl_xor(rs, 8, 64);
      sL[jr] = sL[jr] * scl + rs;
#pragma unroll
      for (int dt = 0; dt < 3; ++dt) oacc[dt][jr] *= scl;
    }

    // PV: A = own-wave P rows (LDS, in-order dep), B = VT direct from L2
    const u16* vtc = vt + c * 128;
#pragma unroll
    for (int ks4 = 0; ks4 < 4; ++ks4) {
      bf16x8 pa = *(const bf16x8*)(Pl + (w * 16 + n) * 128 + ((ks4 * 32 + g * 8) ^ ((n & 7) * 8)));
#pragma unroll
      for (int dt = 0; dt < 3; ++dt) {
        bf16x8 vb = *(const bf16x8*)(vtc + (long)(dt * 16 + n) * NSEQ + ks4 * 32 + g * 8);
        oacc[dt] = __builtin_amdgcn_mfma_f32_16x16x32_bf16(pa, vb, oacc[dt], 0, 0, 0);
      }
    }
  }

  // epilogue: normalize, add (unscaled) Q residual, write f32 + bf16
#pragma unroll
  for (int jr = 0; jr < 4; ++jr) {
    float inv = 1.0f / sL[jr];
    long gr = rowbase + q0 + w * 16 + 4 * g + jr;
#pragma unroll
    for (int dt = 0; dt < 3; ++dt) {
      int col = hc + dt * 16 + n;
      float val = oacc[dt][jr] * inv;
      float q = bf2f(Qb[gr * DV + col]);
      float o = q + val;
      Out[gr * DV + col] = o;
      Ob[gr * DV + col] = f2bf(o);
    }
  }
}

// ---------------- launcher ----------------
extern "C" void kernel_launch(void* const* d_in, const int* in_sizes, int n_in,
                              void* d_out, int out_size, void* d_ws, size_t ws_size,
                              hipStream_t stream) {
  const float* xf = (const float*)d_in[0];
  const float* yf = (const float*)d_in[1];
  const float* wq = (const float*)d_in[2];
  const float* wk = (const float*)d_in[3];
  const float* wv = (const float*)d_in[4];
  const float* w1 = (const float*)d_in[5];
  const float* w2 = (const float*)d_in[6];
  float* Out = (float*)d_out;

  char* ws = (char*)d_ws;
  u16* xb   = (u16*)(ws + 0);          // 6291456
  u16* yb   = (u16*)(ws + 6291456);    // 6291456
  u16* QKVb = (u16*)(ws + 12582912);   // Q,K contiguous (2*6291456)
  u16* Qb   = QKVb;
  u16* Kb   = (u16*)(ws + 18874368);
  u16* VT   = (u16*)(ws + 25165824);   // 6291456: [b][h][48][2048]
  u16* Ob   = (u16*)(ws + 31457280);   // 6291456
  u16* Wqb  = (u16*)(ws + 37748736);   // 294912*3 (Wq,Wk,Wv contiguous)
  u16* Wkb  = (u16*)(ws + 38043648);
  u16* Wvb  = (u16*)(ws + 38338560);
  u16* W1b  = (u16*)(ws + 38633472);   // 1179648
  u16* W2b  = (u16*)(ws + 39813120);   // 1179648
  u16* hid  = (u16*)(ws + 0);          // 25165824, aliases xb/yb/Qb/Kb (dead by FFN1)

  convert_k<<<7728, 256, 0, stream>>>(xf, yf, wq, wk, wv, w1, w2,
                                      xb, yb, Wqb, Wkb, Wvb, W1b, W2b);
  qkv_k<<<dim3(64, 6), 256, 0, stream>>>(xb, yb, Wqb, QKVb);
  vt_k<<<dim3(64, 3), 256, 0, stream>>>(yb, Wvb, VT);
  attn_k<<<512, 512, 0, stream>>>(Qb, Kb, VT, Ob, Out);
  ffn1_k<<<dim3(64, 12), 256, 0, stream>>>(Ob, W1b, hid);
  ffn2_k<<<dim3(64, 3, 2), 256, 0, stream>>>(hid, W2b, Out);
}

// Round 9
// 246.234 us; speedup vs baseline: 1.0981x; 1.0981x over previous
//
#include <hip/hip_runtime.h>
#include <stdint.h>

#define NB 4
#define NSEQ 2048
#define DIN 384
#define DV 384
#define NH 8
#define DH 48
#define DFF 1536
#define MTOT (NB*NSEQ)   // 8192
#define QBLK 128

typedef __attribute__((ext_vector_type(8))) short bf16x8;
typedef __attribute__((ext_vector_type(4))) float f32x4;
typedef unsigned short u16;

#define SCALE2 0.07362222f   // (1/sqrt(384)) * log2(e): softmax in exp2 domain

__device__ __forceinline__ u16 f2bf(float f) {
  unsigned u = __builtin_bit_cast(unsigned, f);
  u = (u + 0x7FFFu + ((u >> 16) & 1u)) >> 16;
  return (u16)u;
}
__device__ __forceinline__ float bf2f(u16 h) {
  unsigned u = ((unsigned)h) << 16;
  return __builtin_bit_cast(float, u);
}
__device__ __forceinline__ float ex2(float x) {   // 2^x, single v_exp_f32
  float r; asm("v_exp_f32 %0, %1" : "=v"(r) : "v"(x)); return r;
}
__device__ __forceinline__ float frcp(float x) {  // fast 1/x
  float r; asm("v_rcp_f32 %0, %1" : "=v"(r) : "v"(x)); return r;
}

// async global->LDS, 16B per lane; LDS dest must be lane-linear (base + lane*16)
__device__ __forceinline__ void gload16(const u16* g, u16* l) {
  __builtin_amdgcn_global_load_lds(
      (const __attribute__((address_space(1))) void*)g,
      (__attribute__((address_space(3))) void*)l, 16, 0, 0);
}

// ---------------- convert f32 -> bf16 (x, y, Wq, Wk, Wv, W1, W2) ----------------
__global__ __launch_bounds__(256) void convert_k(
    const float* __restrict__ xf, const float* __restrict__ yf,
    const float* __restrict__ wq, const float* __restrict__ wk,
    const float* __restrict__ wv, const float* __restrict__ w1,
    const float* __restrict__ w2,
    u16* __restrict__ xb, u16* __restrict__ yb,
    u16* __restrict__ wqb, u16* __restrict__ wkb, u16* __restrict__ wvb,
    u16* __restrict__ w1b, u16* __restrict__ w2b) {
  long i = (long)blockIdx.x * 256 + threadIdx.x;  // 4-elem unit
  const float* src; u16* dst; long u = i;
  if      (u < 786432)  { src = xf; dst = xb; }
  else if (u < 1572864) { u -= 786432;  src = yf; dst = yb; }
  else if (u < 1609728) { u -= 1572864; src = wq; dst = wqb; }
  else if (u < 1646592) { u -= 1609728; src = wk; dst = wkb; }
  else if (u < 1683456) { u -= 1646592; src = wv; dst = wvb; }
  else if (u < 1830912) { u -= 1683456; src = w1; dst = w1b; }
  else                  { u -= 1830912; src = w2; dst = w2b; }
  float4 v = ((const float4*)src)[u];
  ushort4 o;
  o.x = f2bf(v.x); o.y = f2bf(v.y); o.z = f2bf(v.z); o.w = f2bf(v.w);
  ((ushort4*)dst)[u] = o;
}

// ---------------- generic C = A(MxK) * B(NxK)^T tile (128x128, BK=64) ----------------
// A row stride = ldk (enables split-K).  EPI: 0 = store bf16; 1 = gelu(tanh) bf16;
// 2 = atomicAdd f32
template<int EPI>
__device__ __forceinline__ void gemm_tile(const u16* __restrict__ A,
                                          const u16* __restrict__ Bw,
                                          int K, int ldk,
                                          int m0, int n0, int ldc,
                                          u16* __restrict__ Cb,
                                          float* __restrict__ Cf) {
  __shared__ __align__(16) u16 Al[128 * 64];
  __shared__ __align__(16) u16 Bl[128 * 64];
  const int t = threadIdx.x;
  const int l = t & 63, w = t >> 6;
  const int g = l >> 4, nn = l & 15;
  const int wm = w >> 1, wn = w & 1;
  f32x4 acc[4][4] = {};
  const int KT = K >> 6;
  for (int kt = 0; kt < KT; ++kt) {
    const int k0 = kt * 64;
    __syncthreads();   // previous iteration's frag reads done
#pragma unroll
    for (int s = 0; s < 4; ++s) {
      int u = t + 256 * s; int r = u >> 3, ch = u & 7;
      int csw = (ch ^ (r & 7)) * 8;     // inverse-swizzled source column
      gload16(A  + (long)(m0 + r) * ldk + k0 + csw, Al + u * 8);
      gload16(Bw + (long)(n0 + r) * ldk + k0 + csw, Bl + u * 8);
    }
    __syncthreads();   // vmcnt drained, staged data visible
#pragma unroll
    for (int ks = 0; ks < 2; ++ks) {
      const int slot = ((ks * 4 + g) ^ (nn & 7)) * 8;
      bf16x8 af[4], bfr[4];
#pragma unroll
      for (int mt = 0; mt < 4; ++mt)
        af[mt] = *(const bf16x8*)(Al + (wm * 64 + mt * 16 + nn) * 64 + slot);
#pragma unroll
      for (int nt = 0; nt < 4; ++nt)
        bfr[nt] = *(const bf16x8*)(Bl + (wn * 64 + nt * 16 + nn) * 64 + slot);
#pragma unroll
      for (int mt = 0; mt < 4; ++mt)
#pragma unroll
        for (int nt = 0; nt < 4; ++nt)
          acc[mt][nt] = __builtin_amdgcn_mfma_f32_16x16x32_bf16(af[mt], bfr[nt], acc[mt][nt], 0, 0, 0);
    }
  }
  // epilogue
#pragma unroll
  for (int mt = 0; mt < 4; ++mt)
#pragma unroll
    for (int nt = 0; nt < 4; ++nt)
#pragma unroll
      for (int jr = 0; jr < 4; ++jr) {
        int gm = m0 + wm * 64 + mt * 16 + g * 4 + jr;
        int gn = n0 + wn * 64 + nt * 16 + nn;
        float v = acc[mt][nt][jr];
        if (EPI == 0) {
          Cb[(long)gm * ldc + gn] = f2bf(v);
        } else if (EPI == 1) {
          // gelu via tanh approx: 0.5v(1+tanh(0.79788456(v+0.044715 v^3)))
          float inner = 0.7978845608f * v * (1.0f + 0.044715f * v * v);
          float tl = ex2(-2.885390082f * fabsf(inner));   // e^{-2|inner|}
          float th = (1.0f - tl) * frcp(1.0f + tl);
          th = copysignf(th, inner);
          Cb[(long)gm * ldc + gn] = f2bf(0.5f * v * (1.0f + th));
        } else {
          unsafeAtomicAdd(&Cf[(long)gm * ldc + gn], v);
        }
      }
}

// Q,K,V projections: by in [0,9): mat = by/3 (0=Q<-x, 1=K<-y, 2=V<-y), ntile = by%3
__global__ __launch_bounds__(256) void qkv_k(const u16* __restrict__ xb,
                                             const u16* __restrict__ yb,
                                             const u16* __restrict__ Wb,
                                             u16* __restrict__ QKVb) {
  int bx = blockIdx.x;          // 0..63 (M tiles)
  int by = blockIdx.y;          // 0..8
  int mat = by / 3, ntile = by - mat * 3;
  const u16* A = (mat == 0) ? xb : yb;
  const u16* Bw = Wb + (long)mat * (DV * DIN);
  u16* C = QKVb + (long)mat * ((long)MTOT * DV);
  gemm_tile<0>(A, Bw, DIN, DIN, bx * 128, ntile * 128, DV, C, nullptr);
}

__global__ __launch_bounds__(256) void ffn1_k(const u16* __restrict__ Ob,
                                              const u16* __restrict__ W1b,
                                              u16* __restrict__ hid) {
  gemm_tile<1>(Ob, W1b, DV, DV, blockIdx.x * 128, blockIdx.y * 128, DFF, hid, nullptr);
}

// split-K x2: z in {0,1}, K-half = 768, atomicAdd into Out
__global__ __launch_bounds__(256) void ffn2_k(const u16* __restrict__ hid,
                                              const u16* __restrict__ W2b,
                                              float* __restrict__ Out) {
  int z = blockIdx.z;
  gemm_tile<2>(hid + z * 768, W2b + z * 768, 768, DFF,
               blockIdx.x * 128, blockIdx.y * 128, DV, nullptr, Out);
}

// ---------------- single-pass flash attention v5 ----------------
// 512 blocks = (b,h,128-row q-tile); 8 waves x 16-row stripes.
// K: global_load_lds double-buffer prefetched 1 chunk ahead, counted vmcnt(2)
// (vmcnt(0) only on last iter — race fix). V: REGISTER-prefetched 1 chunk ahead
// by waves 5-7 (issued right after barrier B, packed to VTl after next barrier A)
// so V latency hides under a full chunk of compute.
__global__ __launch_bounds__(512) void attn_k(const u16* __restrict__ Qb,
                                              const u16* __restrict__ Kb,
                                              const u16* __restrict__ Vb,
                                              u16* __restrict__ Ob,
                                              float* __restrict__ Out) {
  __shared__ __align__(16) u16 Kl[2][128 * 64];  // dbuf 32KB, swizzled slots
  __shared__ __align__(16) u16 VTl[48 * 128];    // [d][k] 12KB, swizzled
  __shared__ __align__(16) u16 Pl[128 * 128];    // 32KB; Q scratch first

  int bx0 = blockIdx.x;
  int lg = (bx0 & 7) * 64 + (bx0 >> 3);          // XCD swizzle (512 = 8*64, bijective)
  int qt = lg & 15, h = (lg >> 4) & 7, b = lg >> 7;
  const int t = threadIdx.x, l = t & 63, w = t >> 6;
  const int g = l >> 4, n = l & 15;
  const long rowbase = (long)b * NSEQ;
  const int q0 = qt * QBLK;
  const int hc = h * DH;

  // ---- stage Q (pre-scaled, exp2 domain) into Pl scratch [128][64] + zero pads
  for (int i = t; i < 768; i += 512) {
    int r = i / 6, ch = i - r * 6;
    bf16x8 v = *(const bf16x8*)(Qb + (rowbase + q0 + r) * DV + hc + ch * 8);
    bf16x8 sv;
#pragma unroll
    for (int e = 0; e < 8; ++e) sv[e] = (short)f2bf(bf2f((u16)v[e]) * SCALE2);
    *(bf16x8*)(Pl + r * 64 + ch * 8) = sv;
  }
  if (t < 256) {                                  // zero cols 48..63
    int r = t >> 1;
    bf16x8 z = {};
    *(bf16x8*)(Pl + r * 64 + 48 + (t & 1) * 8) = z;
  }
  // issue chunk-0 K stage (cols 48-63 load neighbor-head garbage x Q-zeros = 0)
#pragma unroll
  for (int s = 0; s < 2; ++s) {
    int u = t + 512 * s; int r = u >> 3, ch = u & 7;
    gload16(Kb + (rowbase + r) * DV + hc + ((ch ^ (r & 7)) * 8), &Kl[0][u * 8]);
  }
  // issue chunk-0 V loads into regs (waves 5-7)
  bf16x8 v0, v1, v2, v3;
  int vq = 0, vch = 0;
  if (t >= 320) {
    int j = t - 320;                  // 192 threads
    vq = j & 31; vch = j >> 5;        // 4-row pack, 8-col chunk
    const u16* vbase = Vb + (rowbase + 4 * vq) * DV + hc + vch * 8;
    v0 = *(const bf16x8*)(vbase);
    v1 = *(const bf16x8*)(vbase + DV);
    v2 = *(const bf16x8*)(vbase + 2 * DV);
    v3 = *(const bf16x8*)(vbase + 3 * DV);
  }
  asm volatile("s_waitcnt lgkmcnt(0)" ::: "memory");   // Q ds_writes done
  __builtin_amdgcn_s_barrier();                        // Q visible
  __builtin_amdgcn_sched_barrier(0);

  bf16x8 qa[2];
#pragma unroll
  for (int ks = 0; ks < 2; ++ks)
    qa[ks] = *(const bf16x8*)(Pl + (w * 16 + n) * 64 + ks * 32 + g * 8);

  float mL[4], sL[4];
#pragma unroll
  for (int jr = 0; jr < 4; ++jr) { mL[jr] = -1e30f; sL[jr] = 0.0f; }
  f32x4 oacc[3] = {};

  for (int c = 0; c < 16; ++c) {
    // barrier A: all waves' VTl/Pl reads of chunk c-1 and Kl[(c+1)&1] reads done
    __builtin_amdgcn_s_barrier();
    __builtin_amdgcn_sched_barrier(0);
    // pack V(c) from prefetched regs into VTl (compiler waits their vmcnt here;
    // for waves 5-7 that also drains K(c) — needed this chunk anyway)
    if (t >= 320) {
#pragma unroll
      for (int e = 0; e < 8; ++e) {
        short4 pk; pk.x = v0[e]; pk.y = v1[e]; pk.z = v2[e]; pk.w = v3[e];
        int d = vch * 8 + e;
        *(short4*)(VTl + ((d * 128 + 4 * vq) ^ (e << 3))) = pk;
      }
    }
    __builtin_amdgcn_sched_barrier(0);
    // issue K(c+1) prefetch into other buffer
    if (c + 1 < 16) {
      u16* dst = Kl[(c + 1) & 1];
#pragma unroll
      for (int s = 0; s < 2; ++s) {
        int u = t + 512 * s; int r = u >> 3, ch = u & 7;
        gload16(Kb + (rowbase + (c + 1) * 128 + r) * DV + hc + ((ch ^ (r & 7)) * 8),
                dst + u * 8);
      }
    }
    __builtin_amdgcn_sched_barrier(0);
    // K(c) landed: steady state leaves only K(c+1) in flight; last iter drains all
    if (c < 15) { asm volatile("s_waitcnt vmcnt(2)" ::: "memory"); }
    else        { asm volatile("s_waitcnt vmcnt(0)" ::: "memory"); }
    asm volatile("s_waitcnt lgkmcnt(0)" ::: "memory");   // V^T pack visible
    __builtin_amdgcn_s_barrier();                        // barrier B
    __builtin_amdgcn_sched_barrier(0);

    // issue V(c+1) reg-prefetch now — latency hides under this chunk's compute
    if (t >= 320 && c + 1 < 16) {
      const u16* vbase = Vb + (rowbase + (c + 1) * 128 + 4 * vq) * DV + hc + vch * 8;
      v0 = *(const bf16x8*)(vbase);
      v1 = *(const bf16x8*)(vbase + DV);
      v2 = *(const bf16x8*)(vbase + 2 * DV);
      v3 = *(const bf16x8*)(vbase + 3 * DV);
    }

    const u16* kbuf = Kl[c & 1];
    // QK^T: 16 q-rows x 128 k-cols
    f32x4 sc[8];
#pragma unroll
    for (int jl = 0; jl < 8; ++jl) {
      f32x4 a = {};
#pragma unroll
      for (int ks = 0; ks < 2; ++ks) {
        bf16x8 kb2 = *(const bf16x8*)(kbuf + (jl * 16 + n) * 64 + (((ks * 4 + g) ^ (n & 7)) * 8));
        a = __builtin_amdgcn_mfma_f32_16x16x32_bf16(qa[ks], kb2, a, 0, 0, 0);
      }
      sc[jl] = a;
    }

    // online softmax (exp2 domain), P -> LDS (trunc bf16, swizzled), O rescale
#pragma unroll
    for (int jr = 0; jr < 4; ++jr) {
      float mx = fmaxf(fmaxf(fmaxf(sc[0][jr], sc[1][jr]), fmaxf(sc[2][jr], sc[3][jr])),
                       fmaxf(fmaxf(sc[4][jr], sc[5][jr]), fmaxf(sc[6][jr], sc[7][jr])));
      mx = fmaxf(mx, __shfl_xor(mx, 1, 64));
      mx = fmaxf(mx, __shfl_xor(mx, 2, 64));
      mx = fmaxf(mx, __shfl_xor(mx, 4, 64));
      mx = fmaxf(mx, __shfl_xor(mx, 8, 64));
      float mn = fmaxf(mL[jr], mx);
      float scl = ex2(mL[jr] - mn);
      mL[jr] = mn;
      float rs = 0.0f;
      u16* prl = Pl + (w * 16 + 4 * g + jr) * 128;
      const int pswz = ((4 * g + jr) & 7) << 3;
#pragma unroll
      for (int jl = 0; jl < 8; ++jl) {
        float p = ex2(sc[jl][jr] - mn);
        rs += p;
        prl[(jl * 16 + n) ^ pswz] = (u16)(__builtin_bit_cast(unsigned, p) >> 16);
      }
      rs += __shfl_xor(rs, 1, 64);
      rs += __shfl_xor(rs, 2, 64);
      rs += __shfl_xor(rs, 4, 64);
      rs += __shfl_xor(rs, 8, 64);
      sL[jr] = sL[jr] * scl + rs;
#pragma unroll
      for (int dt = 0; dt < 3; ++dt) oacc[dt][jr] *= scl;
    }

    // PV: own-wave P rows + VTl (in-order LDS dep within wave, no barrier)
#pragma unroll
    for (int ks4 = 0; ks4 < 4; ++ks4) {
      const int slot = ((ks4 * 4 + g) ^ (n & 7)) * 8;
      bf16x8 pa = *(const bf16x8*)(Pl + (w * 16 + n) * 128 + slot);
#pragma unroll
      for (int dt = 0; dt < 3; ++dt) {
        bf16x8 vb = *(const bf16x8*)(VTl + (dt * 16 + n) * 128 + slot);
        oacc[dt] = __builtin_amdgcn_mfma_f32_16x16x32_bf16(pa, vb, oacc[dt], 0, 0, 0);
      }
    }
  }

  // epilogue: normalize, add (unscaled) Q residual, write f32 + bf16
#pragma unroll
  for (int jr = 0; jr < 4; ++jr) {
    float inv = 1.0f / sL[jr];
    long gr = rowbase + q0 + w * 16 + 4 * g + jr;
#pragma unroll
    for (int dt = 0; dt < 3; ++dt) {
      int col = hc + dt * 16 + n;
      float val = oacc[dt][jr] * inv;
      float q = bf2f(Qb[gr * DV + col]);
      float o = q + val;
      Out[gr * DV + col] = o;
      Ob[gr * DV + col] = f2bf(o);
    }
  }
}

// ---------------- launcher ----------------
extern "C" void kernel_launch(void* const* d_in, const int* in_sizes, int n_in,
                              void* d_out, int out_size, void* d_ws, size_t ws_size,
                              hipStream_t stream) {
  const float* xf = (const float*)d_in[0];
  const float* yf = (const float*)d_in[1];
  const float* wq = (const float*)d_in[2];
  const float* wk = (const float*)d_in[3];
  const float* wv = (const float*)d_in[4];
  const float* w1 = (const float*)d_in[5];
  const float* w2 = (const float*)d_in[6];
  float* Out = (float*)d_out;

  char* ws = (char*)d_ws;
  u16* xb   = (u16*)(ws + 0);          // 6291456
  u16* yb   = (u16*)(ws + 6291456);    // 6291456
  u16* QKVb = (u16*)(ws + 12582912);   // Q,K,V contiguous, 3*6291456
  u16* Qb   = QKVb;
  u16* Kb   = (u16*)(ws + 18874368);
  u16* Vb   = (u16*)(ws + 25165824);
  u16* Ob   = (u16*)(ws + 31457280);   // 6291456
  u16* Wqb  = (u16*)(ws + 37748736);   // 294912*3 (Wq,Wk,Wv contiguous)
  u16* Wkb  = (u16*)(ws + 38043648);
  u16* Wvb  = (u16*)(ws + 38338560);
  u16* W1b  = (u16*)(ws + 38633472);   // 1179648
  u16* W2b  = (u16*)(ws + 39813120);   // 1179648
  u16* hid  = (u16*)(ws + 0);          // 25165824, aliases xb/yb/Qb/Kb (dead by FFN1)

  convert_k<<<7728, 256, 0, stream>>>(xf, yf, wq, wk, wv, w1, w2,
                                      xb, yb, Wqb, Wkb, Wvb, W1b, W2b);
  qkv_k<<<dim3(64, 9), 256, 0, stream>>>(xb, yb, Wqb, QKVb);
  attn_k<<<512, 512, 0, stream>>>(Qb, Kb, Vb, Ob, Out);
  ffn1_k<<<dim3(64, 12), 256, 0, stream>>>(Ob, W1b, hid);
  ffn2_k<<<dim3(64, 3, 2), 256, 0, stream>>>(hid, W2b, Out);
}